// Round 1
// baseline (6935.355 us; speedup 1.0000x reference)
//
#include <hip/hip_runtime.h>
#include <cstdint>
#include <cstddef>

typedef __bf16 bf16;
typedef bf16 bf16x4 __attribute__((ext_vector_type(4)));
typedef bf16 bf16x8 __attribute__((ext_vector_type(8)));
typedef float f32x4 __attribute__((ext_vector_type(4)));

#define B_   64
#define T_   512
#define I_   1024
#define H_   1024
#define BT_  32768
#define NB2  128   // lstm blocks
#define NJ   8     // hidden units per lstm block

// ---- ws layout (bytes) ----
#define WS_XBF   ((size_t)0)              // x as bf16 [32768][1024]            : 67108864
#define WS_WXP   ((size_t)67108864)       // Wx^T bf16 [4096][1024]             : 8388608
#define WS_WHP   ((size_t)75497472)       // Wh packed bf16 [128][128][32][8]   : 8388608
#define WS_XG    ((size_t)83886080)       // xg bf16 [512][128][64][32]         : 268435456
#define WS_HB    ((size_t)352321536)      // h dbuf bf16 [2][64][1024]          : 262144
#define WS_CNT   ((size_t)352583680)      // barrier counter                    : 256
#define WS_GL    ((size_t)352583936)      // gate scratch f32 [128][64][32]     : 1048576
#define WS_NEED  ((size_t)353632512)

#define GLD_LDS16(gptr, lptr) \
  __builtin_amdgcn_global_load_lds((const __attribute__((address_space(1))) void*)(gptr), \
                                   (__attribute__((address_space(3))) void*)(lptr), 16, 0, 0)

__device__ __forceinline__ float sigmoidf_(float x) { return 1.0f / (1.0f + __expf(-x)); }

// ---------------- pack kernels ----------------

__global__ __launch_bounds__(256) void k_cvt_x(const float4* __restrict__ in,
                                               bf16* __restrict__ out, int n4) {
  int i = blockIdx.x * blockDim.x + threadIdx.x;
  int stride = gridDim.x * blockDim.x;
  for (; i < n4; i += stride) {
    float4 v = in[i];
    bf16x4 r = { (bf16)v.x, (bf16)v.y, (bf16)v.z, (bf16)v.w };
    *(bf16x4*)(out + (size_t)i * 4) = r;
  }
}

// Wx^T: wxp[(gate*1024 + n)][k] = W[k][n]   (32x32 LDS tile transpose)
__global__ __launch_bounds__(256) void k_pack_wx(const float* __restrict__ W,
                                                 bf16* __restrict__ wxp, int gate) {
  __shared__ bf16 tile[32][33];
  int bx = blockIdx.x & 31, by = blockIdx.x >> 5;
  int tx = threadIdx.x & 31, ty = threadIdx.x >> 5;
  int k0 = by * 32, n0 = bx * 32;
  for (int r = 0; r < 32; r += 8)
    tile[ty + r][tx] = (bf16)W[(size_t)(k0 + ty + r) * H_ + n0 + tx];
  __syncthreads();
  for (int r = 0; r < 32; r += 8)
    wxp[(size_t)(gate * H_ + n0 + ty + r) * I_ + k0 + tx] = tile[tx][ty + r];
}

// Wh packed for LDS fragments: whp[blk][k>>3][gate*8 + (u&7)][k&7] = W[k][u]
__global__ __launch_bounds__(256) void k_pack_wh(const float* __restrict__ W,
                                                 bf16* __restrict__ whp, int gate) {
  __shared__ bf16 tile[32][33];
  int bx = blockIdx.x & 31, by = blockIdx.x >> 5;
  int tx = threadIdx.x & 31, ty = threadIdx.x >> 5;
  int k0 = by * 32, u0 = bx * 32;
  for (int r = 0; r < 32; r += 8)
    tile[ty + r][tx] = (bf16)W[(size_t)(k0 + ty + r) * H_ + u0 + tx];
  __syncthreads();
  for (int r = 0; r < 32; r += 8) {
    int u = u0 + ty + r;
    int k = k0 + tx;
    size_t addr = (size_t)(u >> 3) * 32768 + (size_t)(k >> 3) * 256 +
                  (size_t)(gate * 8 + (u & 7)) * 8 + (k & 7);
    whp[addr] = tile[tx][ty + r];
  }
}

// ---------------- phase 1: xg = x @ Wx  (bf16 MFMA, m97-style) ----------------
// A: xbf [32768][1024], B: wxp [4096][1024] (N-major = B^T), out: xg blocked bf16.
__global__ __launch_bounds__(256) void k_gemm_xg(const bf16* __restrict__ A,
                                                 const bf16* __restrict__ Bt,
                                                 bf16* __restrict__ xg) {
  __shared__ bf16 As[128 * 64];
  __shared__ bf16 Bs[128 * 64];
  int bid = blockIdx.x;
  int bm = bid >> 5, bn = bid & 31;
  int m0 = bm * 128, n0 = bn * 128;
  int tid = threadIdx.x, lane = tid & 63, w = tid >> 6;
  int lr = lane & 15, lk = lane >> 4;
  int sr = lane >> 3, sk = (lane & 7) * 8;
  int wm = (w >> 1) * 64, wn = (w & 1) * 64;
  f32x4 acc[4][4] = {};

  for (int k0 = 0; k0 < 1024; k0 += 64) {
    __syncthreads();
    for (int i = 0; i < 4; ++i) {
      int idx = w * 4 + i;
      const bf16* ga = A + (size_t)(m0 + idx * 8 + sr) * 1024 + k0 + sk;
      GLD_LDS16(ga, &As[idx * 512]);
      const bf16* gb = Bt + (size_t)(n0 + idx * 8 + sr) * 1024 + k0 + sk;
      GLD_LDS16(gb, &Bs[idx * 512]);
    }
    asm volatile("s_waitcnt vmcnt(0)" ::: "memory");
    __syncthreads();
#pragma unroll
    for (int kk = 0; kk < 64; kk += 32) {
      bf16x8 af[4], bfr[4];
#pragma unroll
      for (int i = 0; i < 4; ++i)
        af[i] = *(const bf16x8*)&As[(wm + i * 16 + lr) * 64 + kk + lk * 8];
#pragma unroll
      for (int j = 0; j < 4; ++j)
        bfr[j] = *(const bf16x8*)&Bs[(wn + j * 16 + lr) * 64 + kk + lk * 8];
#pragma unroll
      for (int i = 0; i < 4; ++i)
#pragma unroll
        for (int j = 0; j < 4; ++j)
          acc[i][j] = __builtin_amdgcn_mfma_f32_16x16x32_bf16(af[i], bfr[j], acc[i][j], 0, 0, 0);
    }
  }
  // epilogue: scatter into xg[t][blk][b][c]
#pragma unroll
  for (int i = 0; i < 4; ++i) {
#pragma unroll
    for (int j = 0; j < 4; ++j) {
      int n = n0 + wn + j * 16 + lr;
      int u = n & 1023, g = n >> 10;
      int blk = u >> 3, c = g * 8 + (u & 7);
      int mb = m0 + wm + i * 16 + lk * 4;
#pragma unroll
      for (int r = 0; r < 4; ++r) {
        int m = mb + r;
        int t = m & 511, bb = m >> 9;
        xg[(((size_t)t * NB2 + blk) * B_ + bb) * 32 + c] = (bf16)acc[i][j][r];
      }
    }
  }
}

// ---------------- phase 2: persistent cooperative LSTM scan ----------------
// 128 blocks x 512 threads. Block owns 8 hidden units (32 gate cols).
// Wh slice resident in LDS (64KB). h double-buffered bf16 in global (broadcast).
// c lives in one register per (batch,unit) thread. One grid barrier per step.
__global__ __launch_bounds__(512) void k_lstm(const bf16* __restrict__ xg,
                                              const bf16* __restrict__ whp,
                                              bf16* hb,              // [2][64][1024]
                                              float* __restrict__ out,
                                              unsigned* cnt,
                                              float* gl_all,         // [128][64][32]
                                              const float* __restrict__ bii, const float* __restrict__ bhi,
                                              const float* __restrict__ bif, const float* __restrict__ bhf,
                                              const float* __restrict__ big, const float* __restrict__ bhg,
                                              const float* __restrict__ bio, const float* __restrict__ bho) {
  __shared__ bf16 whl[128 * 32 * 8];   // exactly 64 KB
  int blk = blockIdx.x;
  int tid = threadIdx.x;
  int lane = tid & 63, w = tid >> 6;
  int lr = lane & 15, lk = lane >> 4;
  int wm = (w >> 1) * 16;   // M-tile (batch rows)
  int kh = w & 1;           // K half
  float* gl = gl_all + (size_t)blk * (B_ * 32);

  {  // stage Wh slice: 64KB contiguous
    const bf16* src = whp + (size_t)blk * 32768;
#pragma unroll
    for (int i = 0; i < 8; ++i)
      *(bf16x8*)&whl[(size_t)(i * 512 + tid) * 8] = *(const bf16x8*)&src[(size_t)(i * 512 + tid) * 8];
  }

  int eb = tid >> 3, eu = tid & 7;      // elementwise thread -> (batch, unit)
  int ug = blk * NJ + eu;               // global hidden unit
  float bi = bii[ug] + bhi[ug];
  float bff = bif[ug] + bhf[ug];
  float bg = big[ug] + bhg[ug];
  float bo = bio[ug] + bho[ug];
  float creg = 0.f;
  __syncthreads();

  for (int t = 0; t < T_; ++t) {
    const bf16* hcur = hb + (size_t)(t & 1) * (B_ * H_);
    // prefetch xg gate inputs for this step
    const bf16* xrow = xg + (((size_t)t * NB2 + blk) * B_ + eb) * 32;
    float xgi = (float)xrow[eu];
    float xgf = (float)xrow[8 + eu];
    float xgg = (float)xrow[16 + eu];
    float xgo = (float)xrow[24 + eu];

    // GEMM: g[64][32] = h @ WhSlice   (wave: 16 batch rows, K half, both N-tiles)
    f32x4 acc0 = {}, acc1 = {};
    const bf16* hrow = hcur + (size_t)(wm + lr) * H_;
    int kbase = kh * 512;
#pragma unroll 4
    for (int kk = 0; kk < 512; kk += 32) {
      int k = kbase + kk;
      bf16x8 a = *(const bf16x8*)&hrow[k + lk * 8];
      bf16x8 b0 = *(const bf16x8*)&whl[(((k >> 3) + lk) * 32 + lr) * 8];
      bf16x8 b1 = *(const bf16x8*)&whl[(((k >> 3) + lk) * 32 + 16 + lr) * 8];
      acc0 = __builtin_amdgcn_mfma_f32_16x16x32_bf16(a, b0, acc0, 0, 0, 0);
      acc1 = __builtin_amdgcn_mfma_f32_16x16x32_bf16(a, b1, acc1, 0, 0, 0);
    }
    int gbase = (wm + lk * 4) * 32;
    if (kh == 0) {
#pragma unroll
      for (int r = 0; r < 4; ++r) {
        gl[gbase + r * 32 + lr] = acc0[r];
        gl[gbase + r * 32 + 16 + lr] = acc1[r];
      }
    }
    __syncthreads();
    if (kh == 1) {
#pragma unroll
      for (int r = 0; r < 4; ++r) {
        gl[gbase + r * 32 + lr] += acc0[r];
        gl[gbase + r * 32 + 16 + lr] += acc1[r];
      }
    }
    __syncthreads();

    // gates + state update
    float gi = gl[eb * 32 + eu] + xgi + bi;
    float gf = gl[eb * 32 + 8 + eu] + xgf + bff;
    float gg = gl[eb * 32 + 16 + eu] + xgg + bg;
    float go = gl[eb * 32 + 24 + eu] + xgo + bo;
    float it = sigmoidf_(gi);
    float ft = sigmoidf_(gf);
    float gt = tanhf(gg);
    float ot = sigmoidf_(go);
    creg = ft * creg + it * gt;
    float hval = ot * tanhf(creg);

    bf16* hn = hb + (size_t)((t + 1) & 1) * (B_ * H_);
    hn[(size_t)eb * H_ + ug] = (bf16)hval;
    if (t == T_ - 1) {
      out[(size_t)eb * H_ + ug] = hval;
      out[(size_t)B_ * H_ + eb * H_ + ug] = creg;
      break;  // no barrier needed after last step
    }

    // grid barrier (monotonic counter; zeroed by memset each launch)
    __syncthreads();
    if (tid == 0) {
      __hip_atomic_fetch_add(cnt, 1u, __ATOMIC_ACQ_REL, __HIP_MEMORY_SCOPE_AGENT);
      unsigned tgt = (unsigned)(t + 1) * NB2;
      while (__hip_atomic_load(cnt, __ATOMIC_ACQUIRE, __HIP_MEMORY_SCOPE_AGENT) < tgt)
        __builtin_amdgcn_s_sleep(2);
    }
    __syncthreads();
  }
}

// ---------------- launcher ----------------

extern "C" void kernel_launch(void* const* d_in, const int* in_sizes, int n_in,
                              void* d_out, int out_size, void* d_ws, size_t ws_size,
                              hipStream_t stream) {
  if (ws_size < WS_NEED) return;  // not enough scratch: fail loudly (output stays poisoned)

  const float* x = (const float*)d_in[0];
  const float* W_ii = (const float*)d_in[1];
  const float* W_hi = (const float*)d_in[2];
  const float* W_if = (const float*)d_in[3];
  const float* W_hf = (const float*)d_in[4];
  const float* W_ig = (const float*)d_in[5];
  const float* W_hg = (const float*)d_in[6];
  const float* W_io = (const float*)d_in[7];
  const float* W_ho = (const float*)d_in[8];
  const float* b_ii = (const float*)d_in[9];
  const float* b_hi = (const float*)d_in[10];
  const float* b_if = (const float*)d_in[11];
  const float* b_hf = (const float*)d_in[12];
  const float* b_ig = (const float*)d_in[13];
  const float* b_hg = (const float*)d_in[14];
  const float* b_io = (const float*)d_in[15];
  const float* b_ho = (const float*)d_in[16];

  char* ws = (char*)d_ws;
  bf16* xbf = (bf16*)(ws + WS_XBF);
  bf16* wxp = (bf16*)(ws + WS_WXP);
  bf16* whp = (bf16*)(ws + WS_WHP);
  bf16* xgp = (bf16*)(ws + WS_XG);
  bf16* hbp = (bf16*)(ws + WS_HB);
  unsigned* cntp = (unsigned*)(ws + WS_CNT);
  float* glp = (float*)(ws + WS_GL);
  float* outp = (float*)d_out;

  // zero h0 buffers + barrier counter (contiguous region)
  hipMemsetAsync(ws + WS_HB, 0, 262144 + 256, stream);

  // pack
  k_cvt_x<<<2048, 256, 0, stream>>>((const float4*)x, xbf, BT_ * I_ / 4);
  const float* wx_g[4] = {W_ii, W_if, W_ig, W_io};
  const float* wh_g[4] = {W_hi, W_hf, W_hg, W_ho};
  for (int g = 0; g < 4; ++g) {
    k_pack_wx<<<1024, 256, 0, stream>>>(wx_g[g], wxp, g);
    k_pack_wh<<<1024, 256, 0, stream>>>(wh_g[g], whp, g);
  }

  // phase 1 GEMM
  k_gemm_xg<<<dim3(256 * 32), 256, 0, stream>>>(xbf, wxp, xgp);

  // phase 2 cooperative scan
  void* args[] = {
      (void*)&xgp, (void*)&whp, (void*)&hbp, (void*)&outp, (void*)&cntp, (void*)&glp,
      (void*)&b_ii, (void*)&b_hi, (void*)&b_if, (void*)&b_hf,
      (void*)&b_ig, (void*)&b_hg, (void*)&b_io, (void*)&b_ho};
  hipLaunchCooperativeKernel((const void*)k_lstm, dim3(NB2), dim3(512), args, 0, stream);
}

// Round 2
// 5743.547 us; speedup vs baseline: 1.2075x; 1.2075x over previous
//
#include <hip/hip_runtime.h>
#include <cstdint>
#include <cstddef>

typedef __bf16 bf16;
typedef bf16 bf16x4 __attribute__((ext_vector_type(4)));
typedef bf16 bf16x8 __attribute__((ext_vector_type(8)));
typedef float f32x4 __attribute__((ext_vector_type(4)));

#define B_   64
#define T_   512
#define I_   1024
#define H_   1024
#define BT_  32768
#define NBL  64    // lstm blocks
#define NJ   16    // hidden units per lstm block

// ---- ws layout (bytes) ----
#define WS_XBF   ((size_t)0)              // x as bf16 [32768][1024]            : 67108864
#define WS_WXP   ((size_t)67108864)       // Wx^T bf16 [4096][1024]             : 8388608
#define WS_WHP   ((size_t)75497472)       // Wh packed bf16 [64][128][64][8]    : 8388608
#define WS_XG    ((size_t)83886080)       // xg bf16 [512][64][64][64]          : 268435456
#define WS_HB    ((size_t)352321536)      // h dbuf bf16 [2][64][1024]          : 262144
#define WS_ARR   ((size_t)352583680)      // arrival flags u32[64] @128B stride : 8192
#define WS_GO    ((size_t)352591872)      // go flag                            : 128
#define WS_NEED  ((size_t)352592000)

#define GLD_LDS16(gptr, lptr) \
  __builtin_amdgcn_global_load_lds((const __attribute__((address_space(1))) void*)(gptr), \
                                   (__attribute__((address_space(3))) void*)(lptr), 16, 0, 0)

__device__ __forceinline__ float sigmoidf_(float x) { return 1.0f / (1.0f + __expf(-x)); }

// ---------------- pack kernels ----------------

__global__ __launch_bounds__(256) void k_cvt_x(const float4* __restrict__ in,
                                               bf16* __restrict__ out, int n4) {
  int i = blockIdx.x * blockDim.x + threadIdx.x;
  int stride = gridDim.x * blockDim.x;
  for (; i < n4; i += stride) {
    float4 v = in[i];
    bf16x4 r = { (bf16)v.x, (bf16)v.y, (bf16)v.z, (bf16)v.w };
    *(bf16x4*)(out + (size_t)i * 4) = r;
  }
}

// Wx^T: wxp[(gate*1024 + n)][k] = W[k][n]   (32x32 LDS tile transpose)
__global__ __launch_bounds__(256) void k_pack_wx(const float* __restrict__ W,
                                                 bf16* __restrict__ wxp, int gate) {
  __shared__ bf16 tile[32][33];
  int bx = blockIdx.x & 31, by = blockIdx.x >> 5;
  int tx = threadIdx.x & 31, ty = threadIdx.x >> 5;
  int k0 = by * 32, n0 = bx * 32;
  for (int r = 0; r < 32; r += 8)
    tile[ty + r][tx] = (bf16)W[(size_t)(k0 + ty + r) * H_ + n0 + tx];
  __syncthreads();
  for (int r = 0; r < 32; r += 8)
    wxp[(size_t)(gate * H_ + n0 + ty + r) * I_ + k0 + tx] = tile[tx][ty + r];
}

// Wh packed: whp[blk][k>>3][gate*16 + (u&15)][k&7] = W[k][u],  blk = u>>4
__global__ __launch_bounds__(256) void k_pack_wh(const float* __restrict__ W,
                                                 bf16* __restrict__ whp, int gate) {
  __shared__ bf16 tile[32][33];
  int bx = blockIdx.x & 31, by = blockIdx.x >> 5;
  int tx = threadIdx.x & 31, ty = threadIdx.x >> 5;
  int k0 = by * 32, u0 = bx * 32;
  for (int r = 0; r < 32; r += 8)
    tile[ty + r][tx] = (bf16)W[(size_t)(k0 + ty + r) * H_ + u0 + tx];
  __syncthreads();
  for (int r = 0; r < 32; r += 8) {
    int u = u0 + ty + r;
    int k = k0 + tx;
    size_t addr = ((size_t)(u >> 4) * 128 + (k >> 3)) * 512 +
                  (size_t)(gate * 16 + (u & 15)) * 8 + (k & 7);
    whp[addr] = tile[tx][ty + r];
  }
}

// ---------------- phase 1: xg = x @ Wx  (bf16 MFMA, m97-style) ----------------
__global__ __launch_bounds__(256) void k_gemm_xg(const bf16* __restrict__ A,
                                                 const bf16* __restrict__ Bt,
                                                 bf16* __restrict__ xg) {
  __shared__ bf16 As[128 * 64];
  __shared__ bf16 Bs[128 * 64];
  int bid = blockIdx.x;
  int bm = bid >> 5, bn = bid & 31;
  int m0 = bm * 128, n0 = bn * 128;
  int tid = threadIdx.x, lane = tid & 63, w = tid >> 6;
  int lr = lane & 15, lk = lane >> 4;
  int sr = lane >> 3, sk = (lane & 7) * 8;
  int wm = (w >> 1) * 64, wn = (w & 1) * 64;
  f32x4 acc[4][4] = {};

  for (int k0 = 0; k0 < 1024; k0 += 64) {
    __syncthreads();
    for (int i = 0; i < 4; ++i) {
      int idx = w * 4 + i;
      const bf16* ga = A + (size_t)(m0 + idx * 8 + sr) * 1024 + k0 + sk;
      GLD_LDS16(ga, &As[idx * 512]);
      const bf16* gb = Bt + (size_t)(n0 + idx * 8 + sr) * 1024 + k0 + sk;
      GLD_LDS16(gb, &Bs[idx * 512]);
    }
    asm volatile("s_waitcnt vmcnt(0)" ::: "memory");
    __syncthreads();
#pragma unroll
    for (int kk = 0; kk < 64; kk += 32) {
      bf16x8 af[4], bfr[4];
#pragma unroll
      for (int i = 0; i < 4; ++i)
        af[i] = *(const bf16x8*)&As[(wm + i * 16 + lr) * 64 + kk + lk * 8];
#pragma unroll
      for (int j = 0; j < 4; ++j)
        bfr[j] = *(const bf16x8*)&Bs[(wn + j * 16 + lr) * 64 + kk + lk * 8];
#pragma unroll
      for (int i = 0; i < 4; ++i)
#pragma unroll
        for (int j = 0; j < 4; ++j)
          acc[i][j] = __builtin_amdgcn_mfma_f32_16x16x32_bf16(af[i], bfr[j], acc[i][j], 0, 0, 0);
    }
  }
  // epilogue: scatter into xg[t][blk][b][c],  blk = u>>4, c = gate*16 + (u&15)
#pragma unroll
  for (int i = 0; i < 4; ++i) {
#pragma unroll
    for (int j = 0; j < 4; ++j) {
      int n = n0 + wn + j * 16 + lr;
      int u = n & 1023, g = n >> 10;
      int blk = u >> 4, c = g * 16 + (u & 15);
      int mb = m0 + wm + i * 16 + lk * 4;
#pragma unroll
      for (int r = 0; r < 4; ++r) {
        int m = mb + r;
        int t = m & 511, bb = m >> 9;
        xg[(((size_t)t * NBL + blk) * B_ + bb) * 64 + c] = (bf16)acc[i][j][r];
      }
    }
  }
}

// ---------------- phase 2: persistent cooperative LSTM scan ----------------
// 64 blocks x 512 threads (8 waves). Block owns 16 hidden units (64 gate cols).
// Wh slice resident in LDS (128KB) + gl reduction in LDS (16KB).
// Grid barrier: per-block arrival flags + master broadcast (no atomic RMW).
__global__ __launch_bounds__(512, 1) void k_lstm(const bf16* __restrict__ xg,
                                                 const bf16* __restrict__ whp,
                                                 bf16* hb,              // [2][64][1024]
                                                 float* __restrict__ out,
                                                 unsigned* arr,         // [64] @ 32-u32 stride
                                                 unsigned* go,
                                                 const float* __restrict__ bii, const float* __restrict__ bhi,
                                                 const float* __restrict__ bif, const float* __restrict__ bhf,
                                                 const float* __restrict__ big, const float* __restrict__ bhg,
                                                 const float* __restrict__ bio, const float* __restrict__ bho) {
  __shared__ bf16 whl[65536];          // 128 KB: [k>>3][c][8]
  __shared__ float gl[64 * 64];        // 16 KB:  [b][c]
  int blk = blockIdx.x;
  int tid = threadIdx.x;
  int lane = tid & 63, w = tid >> 6;
  int lr = lane & 15, lk = lane >> 4;
  int wm = (w >> 1) * 16;   // row-group (batch rows)
  int kh = w & 1;           // K half

  {  // stage Wh slice: 128KB contiguous
    const bf16* src = whp + (size_t)blk * 65536;
#pragma unroll
    for (int i = 0; i < 16; ++i)
      *(bf16x8*)&whl[(size_t)(i * 512 + tid) * 8] = *(const bf16x8*)&src[(size_t)(i * 512 + tid) * 8];
  }

  // elementwise mapping: thread -> (u, b0, b1)
  int eu = tid & 15, b0 = tid >> 4, b1 = b0 + 32;
  int ug = blk * NJ + eu;
  float bi = bii[ug] + bhi[ug];
  float bff = bif[ug] + bhf[ug];
  float bg = big[ug] + bhg[ug];
  float bo = bio[ug] + bho[ug];
  float creg0 = 0.f, creg1 = 0.f;

  // preload xg for t=0
  float xv0[4], xv1[4];
  {
    const bf16* xr0 = xg + (((size_t)0 * NBL + blk) * B_ + b0) * 64;
    const bf16* xr1 = xg + (((size_t)0 * NBL + blk) * B_ + b1) * 64;
#pragma unroll
    for (int g = 0; g < 4; ++g) { xv0[g] = (float)xr0[g * 16 + eu]; xv1[g] = (float)xr1[g * 16 + eu]; }
  }
  __syncthreads();

  for (int t = 0; t < T_; ++t) {
    const bf16* hcur = hb + (size_t)(t & 1) * (B_ * H_);

    // GEMM: gl[64][64] = h @ WhSlice.  wave: 16 batch rows x K-half x all 64 cols
    f32x4 acc[4] = {};
    const bf16* hrow = hcur + (size_t)(wm + lr) * H_;
    int kbase = kh * 512;
#pragma unroll 4
    for (int kk = 0; kk < 512; kk += 32) {
      int k = kbase + kk;
      bf16x8 a = *(const bf16x8*)&hrow[k + lk * 8];
#pragma unroll
      for (int nt = 0; nt < 4; ++nt) {
        bf16x8 b = *(const bf16x8*)&whl[((((k >> 3) + lk) * 64 + nt * 16 + lr)) * 8];
        acc[nt] = __builtin_amdgcn_mfma_f32_16x16x32_bf16(a, b, acc[nt], 0, 0, 0);
      }
    }
    int grow = wm + lk * 4;
    if (kh == 0) {
#pragma unroll
      for (int nt = 0; nt < 4; ++nt)
#pragma unroll
        for (int r = 0; r < 4; ++r)
          gl[(grow + r) * 64 + nt * 16 + lr] = acc[nt][r];
    }
    __syncthreads();
    if (kh == 1) {
#pragma unroll
      for (int nt = 0; nt < 4; ++nt)
#pragma unroll
        for (int r = 0; r < 4; ++r)
          gl[(grow + r) * 64 + nt * 16 + lr] += acc[nt][r];
    }
    __syncthreads();

    // gates + state update (2 (b,u) pairs per thread)
    float gi0 = gl[b0 * 64 + eu]      + xv0[0] + bi;
    float gf0 = gl[b0 * 64 + 16 + eu] + xv0[1] + bff;
    float gg0 = gl[b0 * 64 + 32 + eu] + xv0[2] + bg;
    float go0 = gl[b0 * 64 + 48 + eu] + xv0[3] + bo;
    float gi1 = gl[b1 * 64 + eu]      + xv1[0] + bi;
    float gf1 = gl[b1 * 64 + 16 + eu] + xv1[1] + bff;
    float gg1 = gl[b1 * 64 + 32 + eu] + xv1[2] + bg;
    float go1 = gl[b1 * 64 + 48 + eu] + xv1[3] + bo;
    creg0 = sigmoidf_(gf0) * creg0 + sigmoidf_(gi0) * tanhf(gg0);
    creg1 = sigmoidf_(gf1) * creg1 + sigmoidf_(gi1) * tanhf(gg1);
    float hv0 = sigmoidf_(go0) * tanhf(creg0);
    float hv1 = sigmoidf_(go1) * tanhf(creg1);

    bf16* hn = hb + (size_t)((t + 1) & 1) * (B_ * H_);
    hn[(size_t)b0 * H_ + ug] = (bf16)hv0;
    hn[(size_t)b1 * H_ + ug] = (bf16)hv1;
    if (t == T_ - 1) {
      out[(size_t)b0 * H_ + ug] = hv0;
      out[(size_t)b1 * H_ + ug] = hv1;
      out[(size_t)B_ * H_ + b0 * H_ + ug] = creg0;
      out[(size_t)B_ * H_ + b1 * H_ + ug] = creg1;
      break;  // no barrier after last step
    }

    // prefetch xg for t+1 (latency hides under the barrier)
    {
      const bf16* xr0 = xg + (((size_t)(t + 1) * NBL + blk) * B_ + b0) * 64;
      const bf16* xr1 = xg + (((size_t)(t + 1) * NBL + blk) * B_ + b1) * 64;
#pragma unroll
      for (int g = 0; g < 4; ++g) { xv0[g] = (float)xr0[g * 16 + eu]; xv1[g] = (float)xr1[g * 16 + eu]; }
    }

    // grid barrier: parallel arrival flags + master broadcast
    __syncthreads();
    unsigned tgt = (unsigned)(t + 1);
    if (blk == 0) {
      if (tid < 64) {
        if (tid == 0)
          __hip_atomic_store(arr, tgt, __ATOMIC_RELEASE, __HIP_MEMORY_SCOPE_AGENT);
        unsigned v = 0;
        while (!__all((int)(v >= tgt)))
          v = __hip_atomic_load(arr + tid * 32, __ATOMIC_ACQUIRE, __HIP_MEMORY_SCOPE_AGENT);
        if (tid == 0)
          __hip_atomic_store(go, tgt, __ATOMIC_RELEASE, __HIP_MEMORY_SCOPE_AGENT);
      }
    } else {
      if (tid == 0) {
        __hip_atomic_store(arr + blk * 32, tgt, __ATOMIC_RELEASE, __HIP_MEMORY_SCOPE_AGENT);
        while (__hip_atomic_load(go, __ATOMIC_ACQUIRE, __HIP_MEMORY_SCOPE_AGENT) < tgt)
          __builtin_amdgcn_s_sleep(2);
      }
    }
    __syncthreads();
  }
}

// ---------------- launcher ----------------

extern "C" void kernel_launch(void* const* d_in, const int* in_sizes, int n_in,
                              void* d_out, int out_size, void* d_ws, size_t ws_size,
                              hipStream_t stream) {
  if (ws_size < WS_NEED) return;

  const float* x = (const float*)d_in[0];
  const float* W_ii = (const float*)d_in[1];
  const float* W_hi = (const float*)d_in[2];
  const float* W_if = (const float*)d_in[3];
  const float* W_hf = (const float*)d_in[4];
  const float* W_ig = (const float*)d_in[5];
  const float* W_hg = (const float*)d_in[6];
  const float* W_io = (const float*)d_in[7];
  const float* W_ho = (const float*)d_in[8];
  const float* b_ii = (const float*)d_in[9];
  const float* b_hi = (const float*)d_in[10];
  const float* b_if = (const float*)d_in[11];
  const float* b_hf = (const float*)d_in[12];
  const float* b_ig = (const float*)d_in[13];
  const float* b_hg = (const float*)d_in[14];
  const float* b_io = (const float*)d_in[15];
  const float* b_ho = (const float*)d_in[16];

  char* ws = (char*)d_ws;
  bf16* xbf = (bf16*)(ws + WS_XBF);
  bf16* wxp = (bf16*)(ws + WS_WXP);
  bf16* whp = (bf16*)(ws + WS_WHP);
  bf16* xgp = (bf16*)(ws + WS_XG);
  bf16* hbp = (bf16*)(ws + WS_HB);
  unsigned* arrp = (unsigned*)(ws + WS_ARR);
  unsigned* gop = (unsigned*)(ws + WS_GO);
  float* outp = (float*)d_out;

  // zero h0 buffers + arrival flags + go (contiguous region)
  hipMemsetAsync(ws + WS_HB, 0, 262144 + 8192 + 128, stream);

  // pack
  k_cvt_x<<<2048, 256, 0, stream>>>((const float4*)x, xbf, BT_ * I_ / 4);
  const float* wx_g[4] = {W_ii, W_if, W_ig, W_io};
  const float* wh_g[4] = {W_hi, W_hf, W_hg, W_ho};
  for (int g = 0; g < 4; ++g) {
    k_pack_wx<<<1024, 256, 0, stream>>>(wx_g[g], wxp, g);
    k_pack_wh<<<1024, 256, 0, stream>>>(wh_g[g], whp, g);
  }

  // phase 1 GEMM
  k_gemm_xg<<<dim3(256 * 32), 256, 0, stream>>>(xbf, wxp, xgp);

  // phase 2 cooperative scan
  void* args[] = {
      (void*)&xgp, (void*)&whp, (void*)&hbp, (void*)&outp, (void*)&arrp, (void*)&gop,
      (void*)&b_ii, (void*)&b_hi, (void*)&b_if, (void*)&b_hf,
      (void*)&b_ig, (void*)&b_hg, (void*)&b_io, (void*)&b_ho};
  hipLaunchCooperativeKernel((const void*)k_lstm, dim3(NBL), dim3(512), args, 0, stream);
}

// Round 3
// 5578.336 us; speedup vs baseline: 1.2433x; 1.0296x over previous
//
#include <hip/hip_runtime.h>
#include <cstdint>
#include <cstddef>
#include <string.h>

typedef __bf16 bf16;
typedef bf16 bf16x4 __attribute__((ext_vector_type(4)));
typedef bf16 bf16x8 __attribute__((ext_vector_type(8)));
typedef float f32x4 __attribute__((ext_vector_type(4)));
typedef unsigned long long u64;

#define B_   64
#define T_   512
#define I_   1024
#define H_   1024
#define BT_  32768
#define NBL  64    // lstm blocks
#define NJ   16    // hidden units per lstm block

// ---- ws layout (bytes) ----
#define WS_XBF   ((size_t)0)              // x as bf16 [32768][1024]            : 67108864
#define WS_WXP   ((size_t)67108864)       // Wx^T bf16 [4096][1024]             : 8388608
#define WS_WHP   ((size_t)75497472)       // Wh packed bf16 [64][128][64][8]    : 8388608
#define WS_XG    ((size_t)83886080)       // xg bf16 [512][64][64][64]          : 268435456
#define WS_HB    ((size_t)352321536)      // h dbuf bf16 [2][64][1024]          : 262144
#define WS_ARR   ((size_t)352583680)      // arrival flags u32[64] @128B stride : 8192
#define WS_GO    ((size_t)352591872)      // (unused)                           : 128
#define WS_NEED  ((size_t)352592000)

#define GLD_LDS16(gptr, lptr) \
  __builtin_amdgcn_global_load_lds((const __attribute__((address_space(1))) void*)(gptr), \
                                   (__attribute__((address_space(3))) void*)(lptr), 16, 0, 0)

__device__ __forceinline__ float sigmoidf_(float x) { return 1.0f / (1.0f + __expf(-x)); }
__device__ __forceinline__ float lo2f(unsigned u) { unsigned v = u << 16; float f; memcpy(&f, &v, 4); return f; }
__device__ __forceinline__ float hi2f(unsigned u) { unsigned v = u & 0xffff0000u; float f; memcpy(&f, &v, 4); return f; }
__device__ __forceinline__ unsigned short b2s(bf16 h) { unsigned short s; memcpy(&s, &h, 2); return s; }

// ---------------- pack kernels ----------------

__global__ __launch_bounds__(256) void k_cvt_x(const float4* __restrict__ in,
                                               bf16* __restrict__ out, int n4) {
  int i = blockIdx.x * blockDim.x + threadIdx.x;
  int stride = gridDim.x * blockDim.x;
  for (; i < n4; i += stride) {
    float4 v = in[i];
    bf16x4 r = { (bf16)v.x, (bf16)v.y, (bf16)v.z, (bf16)v.w };
    *(bf16x4*)(out + (size_t)i * 4) = r;
  }
}

// Wx^T: wxp[(gate*1024 + n)][k] = W[k][n]   (32x32 LDS tile transpose)
__global__ __launch_bounds__(256) void k_pack_wx(const float* __restrict__ W,
                                                 bf16* __restrict__ wxp, int gate) {
  __shared__ bf16 tile[32][33];
  int bx = blockIdx.x & 31, by = blockIdx.x >> 5;
  int tx = threadIdx.x & 31, ty = threadIdx.x >> 5;
  int k0 = by * 32, n0 = bx * 32;
  for (int r = 0; r < 32; r += 8)
    tile[ty + r][tx] = (bf16)W[(size_t)(k0 + ty + r) * H_ + n0 + tx];
  __syncthreads();
  for (int r = 0; r < 32; r += 8)
    wxp[(size_t)(gate * H_ + n0 + ty + r) * I_ + k0 + tx] = tile[tx][ty + r];
}

// Wh packed: whp[blk][k>>3][gate*16 + (u&15)][k&7] = W[k][u],  blk = u>>4
__global__ __launch_bounds__(256) void k_pack_wh(const float* __restrict__ W,
                                                 bf16* __restrict__ whp, int gate) {
  __shared__ bf16 tile[32][33];
  int bx = blockIdx.x & 31, by = blockIdx.x >> 5;
  int tx = threadIdx.x & 31, ty = threadIdx.x >> 5;
  int k0 = by * 32, u0 = bx * 32;
  for (int r = 0; r < 32; r += 8)
    tile[ty + r][tx] = (bf16)W[(size_t)(k0 + ty + r) * H_ + u0 + tx];
  __syncthreads();
  for (int r = 0; r < 32; r += 8) {
    int u = u0 + ty + r;
    int k = k0 + tx;
    size_t addr = ((size_t)(u >> 4) * 128 + (k >> 3)) * 512 +
                  (size_t)(gate * 16 + (u & 15)) * 8 + (k & 7);
    whp[addr] = tile[tx][ty + r];
  }
}

// ---------------- phase 1: xg = x @ Wx  (bf16 MFMA, m97-style) ----------------
__global__ __launch_bounds__(256) void k_gemm_xg(const bf16* __restrict__ A,
                                                 const bf16* __restrict__ Bt,
                                                 bf16* __restrict__ xg) {
  __shared__ bf16 As[128 * 64];
  __shared__ bf16 Bs[128 * 64];
  int bid = blockIdx.x;
  int bm = bid >> 5, bn = bid & 31;
  int m0 = bm * 128, n0 = bn * 128;
  int tid = threadIdx.x, lane = tid & 63, w = tid >> 6;
  int lr = lane & 15, lk = lane >> 4;
  int sr = lane >> 3, sk = (lane & 7) * 8;
  int wm = (w >> 1) * 64, wn = (w & 1) * 64;
  f32x4 acc[4][4] = {};

  for (int k0 = 0; k0 < 1024; k0 += 64) {
    __syncthreads();
    for (int i = 0; i < 4; ++i) {
      int idx = w * 4 + i;
      const bf16* ga = A + (size_t)(m0 + idx * 8 + sr) * 1024 + k0 + sk;
      GLD_LDS16(ga, &As[idx * 512]);
      const bf16* gb = Bt + (size_t)(n0 + idx * 8 + sr) * 1024 + k0 + sk;
      GLD_LDS16(gb, &Bs[idx * 512]);
    }
    asm volatile("s_waitcnt vmcnt(0)" ::: "memory");
    __syncthreads();
#pragma unroll
    for (int kk = 0; kk < 64; kk += 32) {
      bf16x8 af[4], bfr[4];
#pragma unroll
      for (int i = 0; i < 4; ++i)
        af[i] = *(const bf16x8*)&As[(wm + i * 16 + lr) * 64 + kk + lk * 8];
#pragma unroll
      for (int j = 0; j < 4; ++j)
        bfr[j] = *(const bf16x8*)&Bs[(wn + j * 16 + lr) * 64 + kk + lk * 8];
#pragma unroll
      for (int i = 0; i < 4; ++i)
#pragma unroll
        for (int j = 0; j < 4; ++j)
          acc[i][j] = __builtin_amdgcn_mfma_f32_16x16x32_bf16(af[i], bfr[j], acc[i][j], 0, 0, 0);
    }
  }
  // epilogue: scatter into xg[t][blk][b][c],  blk = u>>4, c = gate*16 + (u&15)
#pragma unroll
  for (int i = 0; i < 4; ++i) {
#pragma unroll
    for (int j = 0; j < 4; ++j) {
      int n = n0 + wn + j * 16 + lr;
      int u = n & 1023, g = n >> 10;
      int blk = u >> 4, c = g * 16 + (u & 15);
      int mb = m0 + wm + i * 16 + lk * 4;
#pragma unroll
      for (int r = 0; r < 4; ++r) {
        int m = mb + r;
        int t = m & 511, bb = m >> 9;
        xg[(((size_t)t * NBL + blk) * B_ + bb) * 64 + c] = (bf16)acc[i][j][r];
      }
    }
  }
}

// ---------------- phase 2: persistent cooperative LSTM scan ----------------
// 64 blocks x 512 threads. Block owns 16 hidden units (64 gate cols).
// Wh in LDS (128KB). h + barrier flags via relaxed AGENT atomics (IF$-coherent,
// no buffer_inv/wbl2). Single-leg all-to-all barrier: store own flag, wave 0
// polls all 64 flags (one per lane).
__global__ __launch_bounds__(512) void k_lstm(const bf16* __restrict__ xg,
                                              const bf16* __restrict__ whp,
                                              bf16* hb,              // [2][64][1024]
                                              float* __restrict__ out,
                                              unsigned* arr,         // [64] @ 32-u32 stride
                                              const float* __restrict__ bii, const float* __restrict__ bhi,
                                              const float* __restrict__ bif, const float* __restrict__ bhf,
                                              const float* __restrict__ big, const float* __restrict__ bhg,
                                              const float* __restrict__ bio, const float* __restrict__ bho) {
  __shared__ bf16 whl[65536];          // 128 KB: [kg][c][8]
  __shared__ float gl[64 * 65];        // padded rows: bank-spread
  int blk = blockIdx.x;
  int tid = threadIdx.x;
  int lane = tid & 63, w = tid >> 6;
  int lr = lane & 15, lk = lane >> 4;
  int wm = (w >> 1) * 16;   // row-group (batch rows)
  int kh = w & 1;           // K half

  {  // stage Wh slice: 128KB contiguous
    const bf16* src = whp + (size_t)blk * 65536;
#pragma unroll
    for (int i = 0; i < 16; ++i)
      *(bf16x8*)&whl[(size_t)(i * 512 + tid) * 8] = *(const bf16x8*)&src[(size_t)(i * 512 + tid) * 8];
  }

  // elementwise mapping: thread -> (batch b, unit pair 2*eu2, 2*eu2+1)
  int eu2 = tid & 7, b = tid >> 3;
  int u0g = blk * NJ + eu2 * 2, u1g = u0g + 1;
  float bi0 = bii[u0g] + bhi[u0g], bi1 = bii[u1g] + bhi[u1g];
  float bf0 = bif[u0g] + bhf[u0g], bf1 = bif[u1g] + bhf[u1g];
  float bg0 = big[u0g] + bhg[u0g], bg1 = big[u1g] + bhg[u1g];
  float bo0 = bio[u0g] + bho[u0g], bo1 = bio[u1g] + bho[u1g];
  float c0 = 0.f, c1 = 0.f;

  // xg preload t=0: 4 u32 words (2 bf16 each), one per gate
  const unsigned* xgw = (const unsigned*)xg;
  unsigned xv[4];
  {
    size_t xb = (((size_t)0 * NBL + blk) * B_ + b) * 32 + eu2;
#pragma unroll
    for (int g = 0; g < 4; ++g) xv[g] = xgw[xb + g * 8];
  }
  __syncthreads();

  for (int t = 0; t < T_; ++t) {
    // ---- grid barrier wait: all flags >= t (skip at t=0) ----
    if (t > 0) {
      if (w == 0) {
        unsigned v;
        do {
          v = __hip_atomic_load(arr + lane * 32, __ATOMIC_RELAXED, __HIP_MEMORY_SCOPE_AGENT);
        } while (!__all((int)(v >= (unsigned)t)));
      }
      __syncthreads();
      __builtin_amdgcn_sched_barrier(0);
    }

    // ---- preload A-fragments (h rows) via relaxed agent atomics (IF$-coherent) ----
    union { u64 q[2]; bf16x8 v; } af[16];
    const u64* hq = (const u64*)hb + (size_t)(t & 1) * 16384 + (wm + lr) * 256 + kh * 128 + lk * 2;
#pragma unroll
    for (int i = 0; i < 16; ++i) {
      af[i].q[0] = __hip_atomic_load(hq + i * 8,     __ATOMIC_RELAXED, __HIP_MEMORY_SCOPE_AGENT);
      af[i].q[1] = __hip_atomic_load(hq + i * 8 + 1, __ATOMIC_RELAXED, __HIP_MEMORY_SCOPE_AGENT);
    }

    // ---- GEMM: gl[64][64] += h @ WhSlice (wave: 16 rows x K-half x 64 cols) ----
    f32x4 acc[4] = {};
#pragma unroll
    for (int i = 0; i < 16; ++i) {
      int kg = kh * 64 + i * 4 + lk;
#pragma unroll
      for (int nt = 0; nt < 4; ++nt) {
        bf16x8 bb = *(const bf16x8*)&whl[(kg * 64 + nt * 16 + lr) * 8];
        acc[nt] = __builtin_amdgcn_mfma_f32_16x16x32_bf16(af[i].v, bb, acc[nt], 0, 0, 0);
      }
    }
    int grow = wm + lk * 4;
    if (kh == 0) {
#pragma unroll
      for (int nt = 0; nt < 4; ++nt)
#pragma unroll
        for (int r = 0; r < 4; ++r)
          gl[(grow + r) * 65 + nt * 16 + lr] = acc[nt][r];
    }
    __syncthreads();
    if (kh == 1) {
#pragma unroll
      for (int nt = 0; nt < 4; ++nt)
#pragma unroll
        for (int r = 0; r < 4; ++r)
          gl[(grow + r) * 65 + nt * 16 + lr] += acc[nt][r];
    }
    __syncthreads();

    // ---- gates + state update (1 batch x 2 units per thread) ----
    int gb = b * 65 + eu2 * 2;
    float gi0 = gl[gb]          + lo2f(xv[0]) + bi0;
    float gi1 = gl[gb + 1]      + hi2f(xv[0]) + bi1;
    float gf0 = gl[gb + 16]     + lo2f(xv[1]) + bf0;
    float gf1 = gl[gb + 17]     + hi2f(xv[1]) + bf1;
    float gg0 = gl[gb + 32]     + lo2f(xv[2]) + bg0;
    float gg1 = gl[gb + 33]     + hi2f(xv[2]) + bg1;
    float go0 = gl[gb + 48]     + lo2f(xv[3]) + bo0;
    float go1 = gl[gb + 49]     + hi2f(xv[3]) + bo1;
    c0 = sigmoidf_(gf0) * c0 + sigmoidf_(gi0) * tanhf(gg0);
    c1 = sigmoidf_(gf1) * c1 + sigmoidf_(gi1) * tanhf(gg1);
    float hv0 = sigmoidf_(go0) * tanhf(c0);
    float hv1 = sigmoidf_(go1) * tanhf(c1);

    if (t == T_ - 1) {
      out[(size_t)b * H_ + u0g] = hv0;
      out[(size_t)b * H_ + u1g] = hv1;
      out[(size_t)B_ * H_ + b * H_ + u0g] = c0;
      out[(size_t)B_ * H_ + b * H_ + u1g] = c1;
      break;  // no barrier after last step
    }

    // ---- publish h(t+1): packed 2xbf16 per thread, relaxed agent store ----
    unsigned hp = (unsigned)b2s((bf16)hv0) | ((unsigned)b2s((bf16)hv1) << 16);
    unsigned* hw = (unsigned*)(hb + (size_t)((t + 1) & 1) * (B_ * H_));
    __hip_atomic_store(hw + b * 512 + blk * 8 + eu2, hp, __ATOMIC_RELAXED, __HIP_MEMORY_SCOPE_AGENT);

    // drain this wave's stores, then block-wide sync, then arm flag
    asm volatile("s_waitcnt vmcnt(0)" ::: "memory");
    __syncthreads();
    if (tid == 0)
      __hip_atomic_store(arr + blk * 32, (unsigned)(t + 1), __ATOMIC_RELAXED, __HIP_MEMORY_SCOPE_AGENT);

    // xg prefetch for t+1 (latency hides under next poll)
    {
      size_t xb = (((size_t)(t + 1) * NBL + blk) * B_ + b) * 32 + eu2;
#pragma unroll
      for (int g = 0; g < 4; ++g) xv[g] = xgw[xb + g * 8];
    }
  }
}

// ---------------- launcher ----------------

extern "C" void kernel_launch(void* const* d_in, const int* in_sizes, int n_in,
                              void* d_out, int out_size, void* d_ws, size_t ws_size,
                              hipStream_t stream) {
  if (ws_size < WS_NEED) return;

  const float* x = (const float*)d_in[0];
  const float* W_ii = (const float*)d_in[1];
  const float* W_hi = (const float*)d_in[2];
  const float* W_if = (const float*)d_in[3];
  const float* W_hf = (const float*)d_in[4];
  const float* W_ig = (const float*)d_in[5];
  const float* W_hg = (const float*)d_in[6];
  const float* W_io = (const float*)d_in[7];
  const float* W_ho = (const float*)d_in[8];
  const float* b_ii = (const float*)d_in[9];
  const float* b_hi = (const float*)d_in[10];
  const float* b_if = (const float*)d_in[11];
  const float* b_hf = (const float*)d_in[12];
  const float* b_ig = (const float*)d_in[13];
  const float* b_hg = (const float*)d_in[14];
  const float* b_io = (const float*)d_in[15];
  const float* b_ho = (const float*)d_in[16];

  char* ws = (char*)d_ws;
  bf16* xbf = (bf16*)(ws + WS_XBF);
  bf16* wxp = (bf16*)(ws + WS_WXP);
  bf16* whp = (bf16*)(ws + WS_WHP);
  bf16* xgp = (bf16*)(ws + WS_XG);
  bf16* hbp = (bf16*)(ws + WS_HB);
  unsigned* arrp = (unsigned*)(ws + WS_ARR);
  float* outp = (float*)d_out;

  // zero h0 buffers + arrival flags (contiguous region)
  hipMemsetAsync(ws + WS_HB, 0, 262144 + 8192 + 128, stream);

  // pack
  k_cvt_x<<<2048, 256, 0, stream>>>((const float4*)x, xbf, BT_ * I_ / 4);
  const float* wx_g[4] = {W_ii, W_if, W_ig, W_io};
  const float* wh_g[4] = {W_hi, W_hf, W_hg, W_ho};
  for (int g = 0; g < 4; ++g) {
    k_pack_wx<<<1024, 256, 0, stream>>>(wx_g[g], wxp, g);
    k_pack_wh<<<1024, 256, 0, stream>>>(wh_g[g], whp, g);
  }

  // phase 1 GEMM
  k_gemm_xg<<<dim3(256 * 32), 256, 0, stream>>>(xbf, wxp, xgp);

  // phase 2 cooperative scan
  void* args[] = {
      (void*)&xgp, (void*)&whp, (void*)&hbp, (void*)&outp, (void*)&arrp,
      (void*)&b_ii, (void*)&b_hi, (void*)&b_if, (void*)&b_hf,
      (void*)&b_ig, (void*)&b_hg, (void*)&b_io, (void*)&b_ho};
  hipLaunchCooperativeKernel((const void*)k_lstm, dim3(NBL), dim3(512), args, 0, stream);
}